// Round 9
// baseline (236.865 us; speedup 1.0000x reference)
//
#include <hip/hip_runtime.h>
#include <hip/hip_bf16.h>
#include <stdint.h>

#define E_EDGES 100000
#define IN_F    256
#define HID     128
#define KNB     16
#define NCHUNK  ((E_EDGES + 63) / 64)   // 1563
#define GEMM_GRID 512

// ---- flat gather parameters ----
// 4 edge-groups (64 edges) per block: longer-lived blocks fix r0's 35%
// occupancy ramp; grid 1563. Slicing abandoned per r8 pre-commit: T is
// L3-resident, so fetch reduction never bought time; flat issue (MLP~17)
// at the random-granule service rate is the best measured structure.
#define GGROUPS     4
#define GATHER_EPB  (GGROUPS * 16)       // 64 edges/block
#define GATHER_GRID ((E_EDGES + GATHER_EPB - 1) / GATHER_EPB)   // 1563

typedef short bf16x8 __attribute__((ext_vector_type(8)));
typedef float f32x4  __attribute__((ext_vector_type(4)));

__device__ __forceinline__ unsigned short f2bf(float f) {
    union { float f; unsigned u; } v; v.f = f;
    unsigned u = v.u;
    u += 0x7fffu + ((u >> 16) & 1u);   // round-to-nearest-even
    return (unsigned short)(u >> 16);
}

// W [256][128] fp32 -> Wtf: bf16 in MFMA B-fragment order. (r0 form)
__global__ void conv_w_kernel(const float* __restrict__ W, unsigned short* __restrict__ Wtf) {
    int d = blockIdx.x * 256 + threadIdx.x;   // 0..4095
    int f = d >> 6, L = d & 63;
    int k0 = f >> 3, ct = f & 7, quad = L >> 4, l15 = L & 15;
    int n  = ct * 16 + l15;
    int kb = (k0 * 4 + quad) * 8;
    const float* wp = W + (size_t)kb * HID + n;
    unsigned short h[8];
    #pragma unroll
    for (int j = 0; j < 8; ++j) h[j] = f2bf(wp[(size_t)j * HID]);
    uint4 o;
    o.x = (unsigned)h[0] | ((unsigned)h[1] << 16);
    o.y = (unsigned)h[2] | ((unsigned)h[3] << 16);
    o.z = (unsigned)h[4] | ((unsigned)h[5] << 16);
    o.w = (unsigned)h[6] | ((unsigned)h[7] << 16);
    *(uint4*)(Wtf + (size_t)d * 8) = o;
}

// T = A @ W + b (A fp32, converted in-reg), stored bf16 [E][128]. (unchanged)
__launch_bounds__(256, 2)
__global__ void gemm_t_kernel(const float* __restrict__ A,
                              const unsigned short* __restrict__ Wtf,
                              const float* __restrict__ bias,
                              unsigned short* __restrict__ T) {
    __shared__ unsigned short Bs[32768];   // 64 KB, fragment order
    const int tid  = threadIdx.x;
    const int wave = tid >> 6;
    const int lane = tid & 63;
    const int l15  = lane & 15;
    const int quad = lane >> 4;

    int c = blockIdx.x;
    int arow = c * 64 + wave * 16 + l15;
    if (arow >= E_EDGES) arow = E_EDGES - 1;
    const float* ap = A + (size_t)arow * IN_F + quad * 8;
    float4 af32[16];
    #pragma unroll
    for (int k0 = 0; k0 < 8; ++k0) {
        af32[2 * k0]     = *(const float4*)(ap + k0 * 32);
        af32[2 * k0 + 1] = *(const float4*)(ap + k0 * 32 + 4);
    }

    #pragma unroll
    for (int it = 0; it < 16; ++it) {
        int d = it * 256 + tid;
        *(uint4*)(Bs + (size_t)d * 8) = *(const uint4*)(Wtf + (size_t)d * 8);
    }

    float4 bv4[8];
    #pragma unroll
    for (int ct = 0; ct < 8; ++ct)
        bv4[ct] = *(const float4*)(bias + ct * 16 + quad * 4);

    __syncthreads();

    for (; c < NCHUNK; c += GEMM_GRID) {
        bf16x8 apre[8];
        #pragma unroll
        for (int k0 = 0; k0 < 8; ++k0) {
            float4 lo = af32[2 * k0], hi = af32[2 * k0 + 1];
            bf16x8 f;
            f[0] = (short)f2bf(lo.x); f[1] = (short)f2bf(lo.y);
            f[2] = (short)f2bf(lo.z); f[3] = (short)f2bf(lo.w);
            f[4] = (short)f2bf(hi.x); f[5] = (short)f2bf(hi.y);
            f[6] = (short)f2bf(hi.z); f[7] = (short)f2bf(hi.w);
            apre[k0] = f;
        }

        {
            int cn = c + GEMM_GRID;
            int arow2 = cn * 64 + wave * 16 + l15;
            if (arow2 >= E_EDGES) arow2 = E_EDGES - 1;
            const float* ap2 = A + (size_t)arow2 * IN_F + quad * 8;
            #pragma unroll
            for (int k0 = 0; k0 < 8; ++k0) {
                af32[2 * k0]     = *(const float4*)(ap2 + k0 * 32);
                af32[2 * k0 + 1] = *(const float4*)(ap2 + k0 * 32 + 4);
            }
        }
        __builtin_amdgcn_sched_barrier(0);

        f32x4 acc[8] = {};
        #pragma unroll
        for (int k0 = 0; k0 < 8; ++k0) {
            #pragma unroll
            for (int ct = 0; ct < 8; ++ct) {
                bf16x8 bf = *(const bf16x8*)(Bs + ((size_t)((k0 * 8 + ct) * 64 + lane)) * 8);
                acc[ct] = __builtin_amdgcn_mfma_f32_16x16x32_bf16(bf, apre[k0], acc[ct], 0, 0, 0);
            }
        }

        const int row = c * 64 + wave * 16 + l15;
        if (row < E_EDGES) {
            unsigned short* tp = T + (size_t)row * HID + quad * 4;
            #pragma unroll
            for (int ct = 0; ct < 8; ++ct) {
                unsigned short h0 = f2bf(acc[ct][0] + bv4[ct].x);
                unsigned short h1 = f2bf(acc[ct][1] + bv4[ct].y);
                unsigned short h2 = f2bf(acc[ct][2] + bv4[ct].z);
                unsigned short h3 = f2bf(acc[ct][3] + bv4[ct].w);
                uint2 o;
                o.x = (unsigned)h0 | ((unsigned)h1 << 16);
                o.y = (unsigned)h2 | ((unsigned)h3 << 16);
                *(uint2*)(tp + ct * 16) = o;
            }
        }
    }
}

// bf16x8 (as uint4) -> two f32x4, BY VALUE (SROA-safe).
__device__ __forceinline__ float u2f(unsigned u) {
    union { unsigned u; float f; } c; c.u = u; return c.f;
}
__device__ __forceinline__ f32x4 declo(uint4 v) {
    f32x4 r = { u2f(v.x << 16), u2f(v.x & 0xffff0000u),
                u2f(v.y << 16), u2f(v.y & 0xffff0000u) };
    return r;
}
__device__ __forceinline__ f32x4 dechi(uint4 v) {
    f32x4 r = { u2f(v.z << 16), u2f(v.z & 0xffff0000u),
                u2f(v.w << 16), u2f(v.w & 0xffff0000u) };
    return r;
}

// out[i] = t[i] + sum_k t[nbr[i][k]]  (fp32 accumulate from bf16 t)
//
// FLAT gather (slicing abandoned per r8 pre-commit: T is L3-resident, fetch
// reduction never bought time; r0's flat 17-load burst is the best measured
// structure at 62 us). r9 refinements over r0:
//  (a) 4 edge-groups per block (grid 1563): longer-lived blocks fix the 35%
//      occupancy ramp of 6250 x 2.5us blocks; groups are independent, so
//      group g's stores overlap group g+1's loads.
//  (b) __launch_bounds__(256,5): VGPR cap 102 (r0 compiled to 52 -> compiler
//      recycled load regs early, throttling MLP below the issued 17).
//  (c) nontemporal out-stores (proven r4-r8): the 51 MB write stream stops
//      evicting T lines from L2.
// Thread map per group: el = tid>>4 (edge), lane = tid&15 (feats lane*8..+8).
__launch_bounds__(256, 5)
__global__ void gather_sum_kernel(const unsigned short* __restrict__ T,
                                  const int* __restrict__ nbr,
                                  float* __restrict__ out) {
    __shared__ int sidx[GATHER_EPB * KNB];   // 64 edges x 16 nbrs = 4 KB

    const int tid   = threadIdx.x;
    const int edge0 = blockIdx.x * GATHER_EPB;

    // Stage neighbor lists: 1024 ints, uint4 per thread, coalesced.
    {
        int g = edge0 * KNB + tid * 4;
        if (g > E_EDGES * KNB - 4) g = E_EDGES * KNB - 4;   // last-block clamp
        *(uint4*)(sidx + tid * 4) = *(const uint4*)(nbr + g);
    }
    __syncthreads();

    const int el   = tid >> 4;        // local edge 0..15
    const int lane = tid & 15;        // feature group: feats [lane*8, lane*8+8)
    const unsigned short* Tb = T + (size_t)lane * 8;

    #pragma unroll 1
    for (int g = 0; g < GGROUPS; ++g) {
        const int eloc = g * 16 + el;            // 0..63
        const int edge = edge0 + eloc;
        const int ecl  = edge < E_EDGES ? edge : E_EDGES - 1;

        // 17 independent row loads, all issued before any use.
        uint4 v[17];
        v[0] = *(const uint4*)(Tb + (size_t)ecl * HID);
        #pragma unroll
        for (int k = 0; k < KNB; ++k) {
            int idx = sidx[eloc * KNB + k];      // broadcast across 16 lanes
            v[k + 1] = *(const uint4*)(Tb + (size_t)idx * HID);
        }
        __builtin_amdgcn_sched_barrier(0);       // keep the load burst together

        f32x4 accL = {0.f, 0.f, 0.f, 0.f};
        f32x4 accH = {0.f, 0.f, 0.f, 0.f};
        #pragma unroll
        for (int k = 0; k < 17; ++k) {
            accL += declo(v[k]);
            accH += dechi(v[k]);
        }

        if (edge < E_EDGES) {
            float* op = out + (size_t)edge * HID + lane * 8;
            __builtin_nontemporal_store(accL, (f32x4*)op);
            __builtin_nontemporal_store(accH, (f32x4*)(op + 4));
        }
    }
}

extern "C" void kernel_launch(void* const* d_in, const int* in_sizes, int n_in,
                              void* d_out, int out_size, void* d_ws, size_t ws_size,
                              hipStream_t stream) {
    const float* edge_feats = (const float*)d_in[0];   // [E, 256] fp32
    const int*   neighbors  = (const int*)d_in[1];     // [E, 16] int32
    const float* W          = (const float*)d_in[2];   // [256, 128] fp32
    const float* b          = (const float*)d_in[3];   // [128] fp32
    float*       out        = (float*)d_out;           // [E, 128] fp32

    unsigned short* Wtf = (unsigned short*)d_ws;                      // 64 KB, fragment order
    unsigned short* T   = (unsigned short*)d_ws + (size_t)IN_F * HID; // 25.6 MB

    conv_w_kernel<<<16, 256, 0, stream>>>(W, Wtf);
    gemm_t_kernel<<<GEMM_GRID, 256, 0, stream>>>(edge_feats, Wtf, b, T);
    gather_sum_kernel<<<GATHER_GRID, 256, 0, stream>>>(T, neighbors, out);
}